// Round 14
// baseline (1081.798 us; speedup 1.0000x reference)
//
#include <hip/hip_runtime.h>

typedef unsigned short u16;
typedef unsigned int u32;
typedef __attribute__((ext_vector_type(8))) _Float16 f16x8;  // 8 fp16 = 4 VGPRs
typedef __attribute__((ext_vector_type(4))) float f32x4;
typedef __attribute__((ext_vector_type(8))) u16 u16x8;

#define N_NODES 20000
#define N_EDGES 320000
#define F_IN 128
#define HID 256
#define OUT_F 32
#define N_LAYERS 30
#define N_GRAPHS 16
#define ELLCAP 64

// ---------------- fp16 helpers ----------------
__device__ __forceinline__ float h2f(u16 u) {
    _Float16 h;
    __builtin_memcpy(&h, &u, 2);
    return (float)h;
}
__device__ __forceinline__ u16 f2h(float f) {
    _Float16 h = (_Float16)f;
    u16 u;
    __builtin_memcpy(&u, &h, 2);
    return u;
}

__device__ __forceinline__ void gl_lds16(const u16* g, u16* l) {
    __builtin_amdgcn_global_load_lds((const u32*)g, (u32*)l, 16, 0, 0);
}

// ---------------- graph build ----------------
// fill_ell also produces the degree: cursor's final value == in-degree at dst.
// ell_col is pre-zeroed; unfilled slots stay 0 (node 0: valid, masked off in agg).
__global__ void fill_ell_kernel(const int* __restrict__ src, const int* __restrict__ dst,
                                int* __restrict__ cursor, u16* __restrict__ ell_col, int E) {
    int e = blockIdx.x * blockDim.x + threadIdx.x;
    if (e >= E) return;
    int s = src[e], d = dst[e];
    int slot = atomicAdd(&cursor[d], 1);
    if (slot < ELLCAP) ell_col[d * ELLCAP + slot] = (u16)s;
}

__global__ void dinv_kernel(const int* __restrict__ cnt, float* __restrict__ dinv, int n) {
    int i = blockIdx.x * blockDim.x + threadIdx.x;
    if (i < n) dinv[i] = rsqrtf((float)(cnt[i] + 1));  // +1 self loop
}

// x' = fp16(dinv ⊙ x): layer-1 gather source (fp16 = the measured numerics floor;
// fp8 failed at 9.3e-6 vs threshold 1.86e-7, R4)
__global__ void prescale_x_kernel(const float* __restrict__ x, const int* __restrict__ cnt,
                                  u16* __restrict__ xs, int total) {
    int i = blockIdx.x * 256 + threadIdx.x;
    if (i < total) xs[i] = f2h(x[i] * rsqrtf((float)(cnt[i >> 7] + 1)));   // F_IN = 128
}

// ---------------- weight transpose to fp16 (LDS-tiled, coalesced writes) ----------------
// W [L][K][N] (f32) -> T [L][N][K] (fp16); 32x32 tiles.
__global__ __launch_bounds__(256) void transpose_f16_tiled(const float* __restrict__ W,
                                                           u16* __restrict__ T,
                                                           int K, int N) {
    __shared__ float tile[32][33];
    const int l = blockIdx.y;
    const int ntn = N >> 5;
    const int kt = blockIdx.x / ntn, ntile = blockIdx.x % ntn;
    const float* Wl = W + (size_t)l * K * N;
    u16* Tl = T + (size_t)l * K * N;
    const int r8 = threadIdx.x >> 5, c = threadIdx.x & 31;
    #pragma unroll
    for (int rr = 0; rr < 4; ++rr) {
        int r = rr * 8 + r8;
        tile[r][c] = Wl[(size_t)(kt * 32 + r) * N + ntile * 32 + c];
    }
    __syncthreads();
    #pragma unroll
    for (int rr = 0; rr < 4; ++rr) {
        int n = rr * 8 + r8;                 // transposed row (N dim)
        float v = tile[c][n];                // W[k=kt*32+c][n]
        Tl[(size_t)(ntile * 32 + n) * K + kt * 32 + c] = f2h(v);
    }
}

// ---------------- fused layer (R14 = R13 + two-slice streamed gather) ----------------
// One kernel per GCN layer. Block = 32 nodes, 256 threads (4 waves). Grid = 625.
// Lineage (measured): R6 bulk 930.9 -> R13 (+pool fusion) 898.4 BEST. Failed/neutral:
// R7 interleave, R9 direct-B, R10 degree-sort, R11 cooperative (graph capture),
// R12 Bs-dbuf.
// R13 counters: FETCH 38.9MB/layer (= 8 XCD x 4.9MB L2-miss refill of the 10.2MB h),
// WRITE 10.0MB (exact), VGPR 68 (huge headroom). Gather runs ~10TB/s effective
// (~29% of L2 peak): depth-2 keeps only 8x16B in flight/wave and 22% of lines miss
// to L3 (~500cy) -> in-order vmcnt exposes a miss-latency per 8-neighbor batch.
// R14: TWO-SLICE STREAMED GATHER — each pass covers feature slices (2q, 2q+1):
//   shared neighbor indices, separate f32 accumulators, 3 rotating load buffers
//   (v0,w0,vn = 96 VGPR) with cross-batch v-prefetch -> 12-16 lines in flight.
//   Issue order v(b), w(b), v(b+1), w(b+1)... is monotone -> in-order vmcnt waits
//   drain exactly the needed batch.
// NUMERICS: per-slice add order (self -> batches asc -> masked tail; j asc, elem
// asc) unchanged from R13 -> absmax must be exactly 1.192093e-07; deviation = bug.
template <int K>
__global__ __launch_bounds__(256, 3) void layer_fused(const u16* __restrict__ hs,
                                                      const u16* __restrict__ B,
                                                      const u16* __restrict__ ell_col,
                                                      const int* __restrict__ cnt,
                                                      const float* __restrict__ dinv,
                                                      const float* __restrict__ bias,
                                                      const float* __restrict__ rowscale,
                                                      const int* __restrict__ batch,
                                                      u16* __restrict__ Ch,
                                                      float* __restrict__ pool_sum) {
    __shared__ u16 cols[32 * ELLCAP];                 // 4 KB
    __shared__ __align__(16) u16 gs[32 * K];          // 16 KB (K=256) / 8 KB (K=128)
    __shared__ __align__(16) u16 Bs[64 * 64 * 4];     // 32 KB: B n-major [256][64k]; last layer: f32 out-stage
    const int node0 = blockIdx.x * 32;
    const int tid = threadIdx.x;
    *(u16x8*)&cols[tid * 8] = *(const u16x8*)&ell_col[(size_t)node0 * ELLCAP + tid * 8];
    const int nd = tid >> 3, sub = tid & 7;
    const int node = node0 + nd;
    int c = cnt[node]; c = c < ELLCAP ? c : ELLCAP;
    const float dd = dinv[node];
    __syncthreads();                                   // cols staged
    const u16* cl = &cols[nd * ELLCAP];
    const int nb = (c + 7) >> 3;                       // 8-batches (last masked)
    constexpr int S = K / 64;

    // ---- phase 1: two-slice streamed aggregate into gs ----
    #pragma unroll 1
    for (int q = 0; q < K / 128; ++q) {
        const int f0 = q * 128 + sub * 8;              // slice 2q
        const int f1 = f0 + 64;                        // slice 2q+1
        f32x4 a00 = {}, a01 = {}, a10 = {}, a11 = {};
        {   // self loop (pre-scaled), both slices
            u16x8 s0 = *(const u16x8*)(hs + (size_t)node * K + f0);
            u16x8 s1 = *(const u16x8*)(hs + (size_t)node * K + f1);
            #pragma unroll
            for (int i = 0; i < 4; ++i) a00[i] += h2f(s0[i]);
            #pragma unroll
            for (int i = 0; i < 4; ++i) a01[i] += h2f(s0[i + 4]);
            #pragma unroll
            for (int i = 0; i < 4; ++i) a10[i] += h2f(s1[i]);
            #pragma unroll
            for (int i = 0; i < 4; ++i) a11[i] += h2f(s1[i + 4]);
        }
        if (nb > 0) {
            u16x8 v0[8], w0[8], vn[8];
            u16x8 cc = *(const u16x8*)&cl[0];
            #pragma unroll
            for (int j = 0; j < 8; ++j) v0[j] = *(const u16x8*)(hs + (size_t)cc[j] * K + f0);
            #pragma unroll
            for (int j = 0; j < 8; ++j) w0[j] = *(const u16x8*)(hs + (size_t)cc[j] * K + f1);
            #pragma unroll 1
            for (int b = 0; b + 1 < nb; ++b) {
                u16x8 ccn = *(const u16x8*)&cl[(b + 1) * 8];
                #pragma unroll
                for (int j = 0; j < 8; ++j) vn[j] = *(const u16x8*)(hs + (size_t)ccn[j] * K + f0);
                // adds of v0 (batch b, slice0): w0(b) and vn(b+1) stay in flight
                #pragma unroll
                for (int j = 0; j < 8; ++j) {
                    #pragma unroll
                    for (int i = 0; i < 4; ++i) a00[i] += h2f(v0[j][i]);
                    #pragma unroll
                    for (int i = 0; i < 4; ++i) a01[i] += h2f(v0[j][i + 4]);
                }
                // adds of w0 (batch b, slice1): vn(b+1) stays in flight
                #pragma unroll
                for (int j = 0; j < 8; ++j) {
                    #pragma unroll
                    for (int i = 0; i < 4; ++i) a10[i] += h2f(w0[j][i]);
                    #pragma unroll
                    for (int i = 0; i < 4; ++i) a11[i] += h2f(w0[j][i + 4]);
                }
                // reuse w0 regs for batch b+1 slice1 (adds done)
                #pragma unroll
                for (int j = 0; j < 8; ++j) w0[j] = *(const u16x8*)(hs + (size_t)ccn[j] * K + f1);
                #pragma unroll
                for (int j = 0; j < 8; ++j) v0[j] = vn[j];
            }
            {   // final masked batch (v0/w0 hold batch nb-1)
                const int base = (nb - 1) * 8;
                const u16x8 zz = {};
                #pragma unroll
                for (int j = 0; j < 8; ++j) {
                    u16x8 t = (base + j < c) ? v0[j] : zz;
                    #pragma unroll
                    for (int i = 0; i < 4; ++i) a00[i] += h2f(t[i]);
                    #pragma unroll
                    for (int i = 0; i < 4; ++i) a01[i] += h2f(t[i + 4]);
                }
                #pragma unroll
                for (int j = 0; j < 8; ++j) {
                    u16x8 t = (base + j < c) ? w0[j] : zz;
                    #pragma unroll
                    for (int i = 0; i < 4; ++i) a10[i] += h2f(t[i]);
                    #pragma unroll
                    for (int i = 0; i < 4; ++i) a11[i] += h2f(t[i + 4]);
                }
            }
        }
        u16x8 o0, o1;
        #pragma unroll
        for (int i = 0; i < 4; ++i) o0[i] = f2h(a00[i] * dd);
        #pragma unroll
        for (int i = 0; i < 4; ++i) o0[i + 4] = f2h(a01[i] * dd);
        #pragma unroll
        for (int i = 0; i < 4; ++i) o1[i] = f2h(a10[i] * dd);
        #pragma unroll
        for (int i = 0; i < 4; ++i) o1[i + 4] = f2h(a11[i] * dd);
        const int cc0 = (2 * q) * 8 + sub;             // global 8-elem chunk indices
        const int cc1 = (2 * q + 1) * 8 + sub;
        *(u16x8*)&gs[nd * K + ((cc0 ^ (nd & 7)) << 3)] = o0;
        *(u16x8*)&gs[nd * K + ((cc1 ^ (nd & 7)) << 3)] = o1;
    }

    // ---- phase 2: GEMM (R6/R13 verbatim: Bs staged via global_load_lds) ----
    const int wave = tid >> 6, lane = tid & 63;
    const int lr = lane >> 3, lc = lane & 7;
    #pragma unroll
    for (int q = 0; q < 8; ++q) {
        int rl = (wave * 8 + q) * 8 + lr;              // B row (n), 0..255
        gl_lds16(B + (size_t)rl * K + ((lc ^ (rl & 7)) << 3), &Bs[(wave * 8 + q) * 512]);
    }
    f32x4 acc[2][4] = {};
    #pragma unroll
    for (int k = 0; k < S; ++k) {
        __syncthreads();                               // gs + Bs(k) ready (drains vmcnt)
        const int k0 = k * 64;
        #pragma unroll
        for (int kk = 0; kk < 2; ++kk) {
            const int c8 = kk * 4 + (lane >> 4);       // chunk within 64-k tile, 0..7
            f16x8 bf[4];
            #pragma unroll
            for (int nt = 0; nt < 4; ++nt) {
                int n = wave * 64 + nt * 16 + (lane & 15);
                bf[nt] = *(const f16x8*)&Bs[n * 64 + ((c8 ^ (n & 7)) << 3)];
            }
            #pragma unroll
            for (int mt = 0; mt < 2; ++mt) {
                int ml = mt * 16 + (lane & 15);
                int cg = (k0 >> 3) + c8;               // global chunk index
                f16x8 af = *(const f16x8*)&gs[ml * K + ((cg ^ (ml & 7)) << 3)];
                #pragma unroll
                for (int nt = 0; nt < 4; ++nt)
                    acc[mt][nt] = __builtin_amdgcn_mfma_f32_16x16x32_f16(af, bf[nt], acc[mt][nt], 0, 0, 0);
            }
        }
        if (k + 1 < S) {
            __syncthreads();                           // all waves done reading Bs(k)
            const int kn = k0 + 64;
            #pragma unroll
            for (int q = 0; q < 8; ++q) {
                int rl = (wave * 8 + q) * 8 + lr;
                gl_lds16(B + (size_t)rl * K + kn + ((lc ^ (rl & 7)) << 3), &Bs[(wave * 8 + q) * 512]);
            }
        }
    }
    // ---- epilogue ----
    // C/D layout col=lane&15, row=(lane>>4)*4+r. Values identical to R13.
    if (Ch) {
        // middle layers: direct fp16 stores (R6 verbatim)
        #pragma unroll
        for (int mt = 0; mt < 2; ++mt) {
            int gr = node0 + mt * 16 + ((lane >> 4) << 2);
            #pragma unroll
            for (int r = 0; r < 4; ++r) {
                float sc = rowscale ? rowscale[gr + r] : 1.f;
                #pragma unroll
                for (int nt = 0; nt < 4; ++nt) {
                    int gc = wave * 64 + nt * 16 + (lane & 15);
                    float v = sc * fmaxf(acc[mt][nt][r] + bias[gc], 0.f);
                    Ch[(size_t)(gr + r) * HID + gc] = f2h(v);
                }
            }
        }
    } else {
        // LAST layer: fused mean-pool contribution (R13). Stage f32 tile in Bs
        // (32KB exact), reduce over sorted-batch row segments, one atomicAdd per
        // (graph,col) segment per block.
        __syncthreads();                               // all GEMM reads of gs/Bs done
        float* Bf = (float*)Bs;                        // 32 x 256 f32
        #pragma unroll
        for (int mt = 0; mt < 2; ++mt) {
            #pragma unroll
            for (int r = 0; r < 4; ++r) {
                int lrow = mt * 16 + ((lane >> 4) << 2) + r;
                #pragma unroll
                for (int nt = 0; nt < 4; ++nt) {
                    int gc = wave * 64 + nt * 16 + (lane & 15);
                    float v = fmaxf(acc[mt][nt][r] + bias[gc], 0.f);
                    Bf[lrow * HID + (gc ^ ((lrow & 7) << 2))] = v;
                }
            }
        }
        __syncthreads();
        const int col = tid;                           // 256 threads = 256 cols
        int gcur = batch[node0];
        float a = 0.f;
        #pragma unroll 1
        for (int i = 0; i < 32; ++i) {
            int g = batch[node0 + i];                  // sorted; broadcast read
            if (g != gcur) { atomicAdd(&pool_sum[gcur * HID + col], a); a = 0.f; gcur = g; }
            a += Bf[i * HID + (col ^ ((i & 7) << 2))];
        }
        atomicAdd(&pool_sum[gcur * HID + col], a);
    }
}

__device__ int lb_int(const int* __restrict__ a, int n, int v) {
    int lo = 0, hi = n;
    while (lo < hi) {
        int mid = (lo + hi) >> 1;
        if (a[mid] < v) lo = mid + 1; else hi = mid;
    }
    return lo;
}

__global__ void final_linear_kernel(const float* __restrict__ pool_sum,
                                    const int* __restrict__ batch,
                                    const float* __restrict__ Wlin,
                                    const float* __restrict__ blin,
                                    float* __restrict__ out) {
    int idx = blockIdx.x * blockDim.x + threadIdx.x;
    if (idx >= N_GRAPHS * OUT_F) return;
    int g = idx / OUT_F, o = idx % OUT_F;
    int lo = lb_int(batch, N_NODES, g);
    int hi = lb_int(batch, N_NODES, g + 1);
    float cinv = 1.f / fmaxf((float)(hi - lo), 1.f);
    float s = blin[o];
    for (int k = 0; k < HID; ++k) s += (pool_sum[g * HID + k] * cinv) * Wlin[k * OUT_F + o];
    out[idx] = s;
}

// ---------------- launch ----------------
static inline size_t align_up(size_t x, size_t a) { return (x + a - 1) & ~(a - 1); }

extern "C" void kernel_launch(void* const* d_in, const int* in_sizes, int n_in,
                              void* d_out, int out_size, void* d_ws, size_t ws_size,
                              hipStream_t stream) {
    const float* x     = (const float*)d_in[0];
    const int*   elist = (const int*)d_in[1];   // [2, E]
    const int*   batch = (const int*)d_in[2];
    const float* W1    = (const float*)d_in[3];
    const float* b1    = (const float*)d_in[4];
    const float* Wm    = (const float*)d_in[5];
    const float* bm    = (const float*)d_in[6];
    const float* Wlin  = (const float*)d_in[7];
    const float* blin  = (const float*)d_in[8];
    float* outp = (float*)d_out;

    const int* srcA = elist;
    const int* dstA = elist + N_EDGES;

    char* ws = (char*)d_ws;
    size_t off = 0;
    u16*   hA     = (u16*)(ws + off);   off = align_up(off + sizeof(u16) * N_NODES * HID, 1024);
    u16*   hB     = (u16*)(ws + off);   off = align_up(off + sizeof(u16) * N_NODES * HID, 1024);
    u16*   xs     = (u16*)(ws + off);   off = align_up(off + sizeof(u16) * N_NODES * F_IN, 1024);
    u16*   W1T    = (u16*)(ws + off);   off = align_up(off + sizeof(u16) * F_IN * HID, 1024);
    u16*   WmT    = (u16*)(ws + off);   off = align_up(off + sizeof(u16) * (N_LAYERS - 1) * HID * HID, 1024);
    int*   cursor = (int*)(ws + off);   off = align_up(off + sizeof(int) * N_NODES, 1024);
    float* dinv   = (float*)(ws + off); off = align_up(off + sizeof(float) * N_NODES, 1024);
    u16*   ell_col = (u16*)(ws + off);  off = align_up(off + sizeof(u16) * N_NODES * ELLCAP, 1024);
    float* pool_sum = (float*)(ws + off); off = align_up(off + sizeof(float) * N_GRAPHS * HID, 1024);

    hipMemsetAsync(cursor, 0, sizeof(int) * N_NODES, stream);
    hipMemsetAsync(ell_col, 0, sizeof(u16) * N_NODES * ELLCAP, stream);  // pad slots -> node 0 (masked)
    hipMemsetAsync(pool_sum, 0, sizeof(float) * N_GRAPHS * HID, stream);

    fill_ell_kernel<<<(N_EDGES + 255) / 256, 256, 0, stream>>>(srcA, dstA, cursor, ell_col, N_EDGES);
    dinv_kernel<<<(N_NODES + 255) / 256, 256, 0, stream>>>(cursor, dinv, N_NODES);
    prescale_x_kernel<<<(N_NODES * F_IN + 255) / 256, 256, 0, stream>>>(x, cursor, xs, N_NODES * F_IN);

    transpose_f16_tiled<<<dim3((F_IN / 32) * (HID / 32), 1), 256, 0, stream>>>(W1, W1T, F_IN, HID);
    transpose_f16_tiled<<<dim3((HID / 32) * (HID / 32), N_LAYERS - 1), 256, 0, stream>>>(Wm, WmT, HID, HID);

    const int lgrid = N_NODES / 32;   // 625, exact
    // layer 1: K = F_IN, gather from xs, write fp16 hA (double-buffer ping-pong after)
    layer_fused<F_IN><<<lgrid, 256, 0, stream>>>(xs, W1T, ell_col, cursor, dinv, b1, dinv,
                                                 batch, hA, pool_sum);
    u16* cur = hA; u16* nxt = hB;
    for (int l = 0; l < N_LAYERS - 1; ++l) {
        const bool last = (l == N_LAYERS - 2);
        layer_fused<HID><<<lgrid, 256, 0, stream>>>(cur, WmT + (size_t)l * HID * HID,
                                                    ell_col, cursor, dinv,
                                                    bm + (size_t)l * HID,
                                                    last ? nullptr : dinv,
                                                    batch,
                                                    last ? nullptr : nxt, pool_sum);
        u16* t = cur; cur = nxt; nxt = t;
    }
    final_linear_kernel<<<2, 256, 0, stream>>>(pool_sum, batch, Wlin, blin, outp);
}

// Round 15
// 901.908 us; speedup vs baseline: 1.1995x; 1.1995x over previous
//
#include <hip/hip_runtime.h>

typedef unsigned short u16;
typedef unsigned int u32;
typedef __attribute__((ext_vector_type(8))) _Float16 f16x8;  // 8 fp16 = 4 VGPRs
typedef __attribute__((ext_vector_type(4))) float f32x4;
typedef __attribute__((ext_vector_type(8))) u16 u16x8;

#define N_NODES 20000
#define N_EDGES 320000
#define F_IN 128
#define HID 256
#define OUT_F 32
#define N_LAYERS 30
#define N_GRAPHS 16
#define ELLCAP 64

// ---------------- fp16 helpers ----------------
__device__ __forceinline__ float h2f(u16 u) {
    _Float16 h;
    __builtin_memcpy(&h, &u, 2);
    return (float)h;
}
__device__ __forceinline__ u16 f2h(float f) {
    _Float16 h = (_Float16)f;
    u16 u;
    __builtin_memcpy(&u, &h, 2);
    return u;
}

__device__ __forceinline__ void gl_lds16(const u16* g, u16* l) {
    __builtin_amdgcn_global_load_lds((const u32*)g, (u32*)l, 16, 0, 0);
}

// ---------------- graph build ----------------
// fill_ell also produces the degree: cursor's final value == in-degree at dst.
// ell_col is pre-zeroed; unfilled slots stay 0 (node 0: valid, masked off in agg).
__global__ void fill_ell_kernel(const int* __restrict__ src, const int* __restrict__ dst,
                                int* __restrict__ cursor, u16* __restrict__ ell_col, int E) {
    int e = blockIdx.x * blockDim.x + threadIdx.x;
    if (e >= E) return;
    int s = src[e], d = dst[e];
    int slot = atomicAdd(&cursor[d], 1);
    if (slot < ELLCAP) ell_col[d * ELLCAP + slot] = (u16)s;
}

__global__ void dinv_kernel(const int* __restrict__ cnt, float* __restrict__ dinv, int n) {
    int i = blockIdx.x * blockDim.x + threadIdx.x;
    if (i < n) dinv[i] = rsqrtf((float)(cnt[i] + 1));  // +1 self loop
}

// x' = fp16(dinv ⊙ x): layer-1 gather source (fp16 = the measured numerics floor;
// fp8 failed at 9.3e-6 vs threshold 1.86e-7, R4)
__global__ void prescale_x_kernel(const float* __restrict__ x, const int* __restrict__ cnt,
                                  u16* __restrict__ xs, int total) {
    int i = blockIdx.x * 256 + threadIdx.x;
    if (i < total) xs[i] = f2h(x[i] * rsqrtf((float)(cnt[i >> 7] + 1)));   // F_IN = 128
}

// ---------------- weight transpose to fp16 (LDS-tiled, coalesced writes) ----------------
// W [L][K][N] (f32) -> T [L][N][K] (fp16); 32x32 tiles.
__global__ __launch_bounds__(256) void transpose_f16_tiled(const float* __restrict__ W,
                                                           u16* __restrict__ T,
                                                           int K, int N) {
    __shared__ float tile[32][33];
    const int l = blockIdx.y;
    const int ntn = N >> 5;
    const int kt = blockIdx.x / ntn, ntile = blockIdx.x % ntn;
    const float* Wl = W + (size_t)l * K * N;
    u16* Tl = T + (size_t)l * K * N;
    const int r8 = threadIdx.x >> 5, c = threadIdx.x & 31;
    #pragma unroll
    for (int rr = 0; rr < 4; ++rr) {
        int r = rr * 8 + r8;
        tile[r][c] = Wl[(size_t)(kt * 32 + r) * N + ntile * 32 + c];
    }
    __syncthreads();
    #pragma unroll
    for (int rr = 0; rr < 4; ++rr) {
        int n = rr * 8 + r8;                 // transposed row (N dim)
        float v = tile[c][n];                // W[k=kt*32+c][n]
        Tl[(size_t)(ntile * 32 + n) * K + kt * 32 + c] = f2h(v);
    }
}

// ---------------- fused layer (R15 = R13 verbatim, the measured best: 898.4us) ----------------
// One kernel per GCN layer. Block = 32 nodes, 256 threads (4 waves). Grid = 625.
// FINAL LEDGER (all measured):
//   R6 bulk-fused 930.9 -> R13 (+last-layer pool fusion) 898.4 BEST.
//   Failed/neutral intra-layer variants: R7 slice-interleave +370 (barrier serial +
//   VGPR choke), R9 direct-B +147 (scattered L2 requests), R10 degree-sort +148
//   (sort prologue cost; divergence null), R11 cooperative (rejected under graph
//   capture), R12 Bs-dbuf +22 (staging already TLP-hidden), R14 deep-ILP gather
//   +183 (3x8 u16x8 bufs = 96 VGPR -> spills under bounds(256,3)).
// Floor model (R13 counters): gather latency hidden by cross-block TLP, bound by
// per-XCD L2 line-service (~14K lines/us); h 10.2MB > 4MiB L2/XCD (FETCH 38.9MB/
// layer = 8 XCD refills); fp16 = numerics floor; per-layer ~28.7us ~ structural.
template <int K>
__global__ __launch_bounds__(256, 3) void layer_fused(const u16* __restrict__ hs,
                                                      const u16* __restrict__ B,
                                                      const u16* __restrict__ ell_col,
                                                      const int* __restrict__ cnt,
                                                      const float* __restrict__ dinv,
                                                      const float* __restrict__ bias,
                                                      const float* __restrict__ rowscale,
                                                      const int* __restrict__ batch,
                                                      u16* __restrict__ Ch,
                                                      float* __restrict__ pool_sum) {
    __shared__ u16 cols[32 * ELLCAP];                 // 4 KB
    __shared__ __align__(16) u16 gs[32 * K];          // 16 KB (K=256) / 8 KB (K=128)
    __shared__ __align__(16) u16 Bs[64 * 64 * 4];     // 32 KB: B n-major [256][64k]; last layer: f32 out-stage
    const int node0 = blockIdx.x * 32;
    const int tid = threadIdx.x;
    *(u16x8*)&cols[tid * 8] = *(const u16x8*)&ell_col[(size_t)node0 * ELLCAP + tid * 8];
    const int nd = tid >> 3, sub = tid & 7;
    const int node = node0 + nd;
    int c = cnt[node]; c = c < ELLCAP ? c : ELLCAP;
    const float dd = dinv[node];
    __syncthreads();                                   // cols staged
    const u16* cl = &cols[nd * ELLCAP];
    const int nb = (c + 7) >> 3;                       // 8-batches (last masked)
    constexpr int S = K / 64;

    // ---- phase 1: aggregate into gs (R6 verbatim) ----
    #pragma unroll 1
    for (int p = 0; p < S; ++p) {
        const int f = p * 64 + sub * 8;
        f32x4 a0 = {}, a1 = {};
        {   // self loop (pre-scaled)
            u16x8 sv = *(const u16x8*)(hs + (size_t)node * K + f);
            #pragma unroll
            for (int i = 0; i < 4; ++i) a0[i] += h2f(sv[i]);
            #pragma unroll
            for (int i = 0; i < 4; ++i) a1[i] += h2f(sv[i + 4]);
        }
        if (nb > 0) {
            u16x8 vbuf[8];
            u16x8 cc = *(const u16x8*)&cl[0];
            #pragma unroll
            for (int j = 0; j < 8; ++j) vbuf[j] = *(const u16x8*)(hs + (size_t)cc[j] * K + f);
            int base = 0;
            for (int b = 1; b < nb; ++b) {
                u16x8 cn = *(const u16x8*)&cl[b * 8];
                u16x8 vn[8];
                #pragma unroll
                for (int j = 0; j < 8; ++j) vn[j] = *(const u16x8*)(hs + (size_t)cn[j] * K + f);
                #pragma unroll
                for (int j = 0; j < 8; ++j) {
                    #pragma unroll
                    for (int i = 0; i < 4; ++i) a0[i] += h2f(vbuf[j][i]);
                    #pragma unroll
                    for (int i = 0; i < 4; ++i) a1[i] += h2f(vbuf[j][i + 4]);
                }
                base += 8;
                #pragma unroll
                for (int j = 0; j < 8; ++j) vbuf[j] = vn[j];
            }
            const u16x8 zz = {};
            #pragma unroll
            for (int j = 0; j < 8; ++j) {
                u16x8 v = (base + j < c) ? vbuf[j] : zz;   // masked final batch
                #pragma unroll
                for (int i = 0; i < 4; ++i) a0[i] += h2f(v[i]);
                #pragma unroll
                for (int i = 0; i < 4; ++i) a1[i] += h2f(v[i + 4]);
            }
        }
        u16x8 o;
        #pragma unroll
        for (int i = 0; i < 4; ++i) o[i] = f2h(a0[i] * dd);
        #pragma unroll
        for (int i = 0; i < 4; ++i) o[i + 4] = f2h(a1[i] * dd);
        const int cc_ = p * 8 + sub;                   // global 8-elem chunk index
        *(u16x8*)&gs[nd * K + ((cc_ ^ (nd & 7)) << 3)] = o;
    }

    // ---- phase 2: GEMM (R6 verbatim: Bs staged via global_load_lds) ----
    const int wave = tid >> 6, lane = tid & 63;
    const int lr = lane >> 3, lc = lane & 7;
    #pragma unroll
    for (int q = 0; q < 8; ++q) {
        int rl = (wave * 8 + q) * 8 + lr;              // B row (n), 0..255
        gl_lds16(B + (size_t)rl * K + ((lc ^ (rl & 7)) << 3), &Bs[(wave * 8 + q) * 512]);
    }
    f32x4 acc[2][4] = {};
    #pragma unroll
    for (int k = 0; k < S; ++k) {
        __syncthreads();                               // gs + Bs(k) ready (drains vmcnt)
        const int k0 = k * 64;
        #pragma unroll
        for (int kk = 0; kk < 2; ++kk) {
            const int c8 = kk * 4 + (lane >> 4);       // chunk within 64-k tile, 0..7
            f16x8 bf[4];
            #pragma unroll
            for (int nt = 0; nt < 4; ++nt) {
                int n = wave * 64 + nt * 16 + (lane & 15);
                bf[nt] = *(const f16x8*)&Bs[n * 64 + ((c8 ^ (n & 7)) << 3)];
            }
            #pragma unroll
            for (int mt = 0; mt < 2; ++mt) {
                int ml = mt * 16 + (lane & 15);
                int cg = (k0 >> 3) + c8;               // global chunk index
                f16x8 af = *(const f16x8*)&gs[ml * K + ((cg ^ (ml & 7)) << 3)];
                #pragma unroll
                for (int nt = 0; nt < 4; ++nt)
                    acc[mt][nt] = __builtin_amdgcn_mfma_f32_16x16x32_f16(af, bf[nt], acc[mt][nt], 0, 0, 0);
            }
        }
        if (k + 1 < S) {
            __syncthreads();                           // all waves done reading Bs(k)
            const int kn = k0 + 64;
            #pragma unroll
            for (int q = 0; q < 8; ++q) {
                int rl = (wave * 8 + q) * 8 + lr;
                gl_lds16(B + (size_t)rl * K + kn + ((lc ^ (rl & 7)) << 3), &Bs[(wave * 8 + q) * 512]);
            }
        }
    }
    // ---- epilogue ----
    // C/D layout col=lane&15, row=(lane>>4)*4+r. Values identical to R6.
    if (Ch) {
        // middle layers: direct fp16 stores (R6 verbatim)
        #pragma unroll
        for (int mt = 0; mt < 2; ++mt) {
            int gr = node0 + mt * 16 + ((lane >> 4) << 2);
            #pragma unroll
            for (int r = 0; r < 4; ++r) {
                float sc = rowscale ? rowscale[gr + r] : 1.f;
                #pragma unroll
                for (int nt = 0; nt < 4; ++nt) {
                    int gc = wave * 64 + nt * 16 + (lane & 15);
                    float v = sc * fmaxf(acc[mt][nt][r] + bias[gc], 0.f);
                    Ch[(size_t)(gr + r) * HID + gc] = f2h(v);
                }
            }
        }
    } else {
        // LAST layer: fused mean-pool contribution. Stage f32 tile in Bs (32KB
        // exact), reduce over sorted-batch row segments, one atomicAdd per
        // (graph,col) segment per block.
        __syncthreads();                               // all GEMM reads of gs/Bs done
        float* Bf = (float*)Bs;                        // 32 x 256 f32
        #pragma unroll
        for (int mt = 0; mt < 2; ++mt) {
            #pragma unroll
            for (int r = 0; r < 4; ++r) {
                int lrow = mt * 16 + ((lane >> 4) << 2) + r;
                #pragma unroll
                for (int nt = 0; nt < 4; ++nt) {
                    int gc = wave * 64 + nt * 16 + (lane & 15);
                    float v = fmaxf(acc[mt][nt][r] + bias[gc], 0.f);
                    Bf[lrow * HID + (gc ^ ((lrow & 7) << 2))] = v;
                }
            }
        }
        __syncthreads();
        const int col = tid;                           // 256 threads = 256 cols
        int gcur = batch[node0];
        float a = 0.f;
        #pragma unroll 1
        for (int i = 0; i < 32; ++i) {
            int g = batch[node0 + i];                  // sorted; broadcast read
            if (g != gcur) { atomicAdd(&pool_sum[gcur * HID + col], a); a = 0.f; gcur = g; }
            a += Bf[i * HID + (col ^ ((i & 7) << 2))];
        }
        atomicAdd(&pool_sum[gcur * HID + col], a);
    }
}

__device__ int lb_int(const int* __restrict__ a, int n, int v) {
    int lo = 0, hi = n;
    while (lo < hi) {
        int mid = (lo + hi) >> 1;
        if (a[mid] < v) lo = mid + 1; else hi = mid;
    }
    return lo;
}

__global__ void final_linear_kernel(const float* __restrict__ pool_sum,
                                    const int* __restrict__ batch,
                                    const float* __restrict__ Wlin,
                                    const float* __restrict__ blin,
                                    float* __restrict__ out) {
    int idx = blockIdx.x * blockDim.x + threadIdx.x;
    if (idx >= N_GRAPHS * OUT_F) return;
    int g = idx / OUT_F, o = idx % OUT_F;
    int lo = lb_int(batch, N_NODES, g);
    int hi = lb_int(batch, N_NODES, g + 1);
    float cinv = 1.f / fmaxf((float)(hi - lo), 1.f);
    float s = blin[o];
    for (int k = 0; k < HID; ++k) s += (pool_sum[g * HID + k] * cinv) * Wlin[k * OUT_F + o];
    out[idx] = s;
}

// ---------------- launch ----------------
static inline size_t align_up(size_t x, size_t a) { return (x + a - 1) & ~(a - 1); }

extern "C" void kernel_launch(void* const* d_in, const int* in_sizes, int n_in,
                              void* d_out, int out_size, void* d_ws, size_t ws_size,
                              hipStream_t stream) {
    const float* x     = (const float*)d_in[0];
    const int*   elist = (const int*)d_in[1];   // [2, E]
    const int*   batch = (const int*)d_in[2];
    const float* W1    = (const float*)d_in[3];
    const float* b1    = (const float*)d_in[4];
    const float* Wm    = (const float*)d_in[5];
    const float* bm    = (const float*)d_in[6];
    const float* Wlin  = (const float*)d_in[7];
    const float* blin  = (const float*)d_in[8];
    float* outp = (float*)d_out;

    const int* srcA = elist;
    const int* dstA = elist + N_EDGES;

    char* ws = (char*)d_ws;
    size_t off = 0;
    u16*   hA     = (u16*)(ws + off);   off = align_up(off + sizeof(u16) * N_NODES * HID, 1024);
    u16*   hB     = (u16*)(ws + off);   off = align_up(off + sizeof(u16) * N_NODES * HID, 1024);
    u16*   xs     = (u16*)(ws + off);   off = align_up(off + sizeof(u16) * N_NODES * F_IN, 1024);
    u16*   W1T    = (u16*)(ws + off);   off = align_up(off + sizeof(u16) * F_IN * HID, 1024);
    u16*   WmT    = (u16*)(ws + off);   off = align_up(off + sizeof(u16) * (N_LAYERS - 1) * HID * HID, 1024);
    int*   cursor = (int*)(ws + off);   off = align_up(off + sizeof(int) * N_NODES, 1024);
    float* dinv   = (float*)(ws + off); off = align_up(off + sizeof(float) * N_NODES, 1024);
    u16*   ell_col = (u16*)(ws + off);  off = align_up(off + sizeof(u16) * N_NODES * ELLCAP, 1024);
    float* pool_sum = (float*)(ws + off); off = align_up(off + sizeof(float) * N_GRAPHS * HID, 1024);

    hipMemsetAsync(cursor, 0, sizeof(int) * N_NODES, stream);
    hipMemsetAsync(ell_col, 0, sizeof(u16) * N_NODES * ELLCAP, stream);  // pad slots -> node 0 (masked)
    hipMemsetAsync(pool_sum, 0, sizeof(float) * N_GRAPHS * HID, stream);

    fill_ell_kernel<<<(N_EDGES + 255) / 256, 256, 0, stream>>>(srcA, dstA, cursor, ell_col, N_EDGES);
    dinv_kernel<<<(N_NODES + 255) / 256, 256, 0, stream>>>(cursor, dinv, N_NODES);
    prescale_x_kernel<<<(N_NODES * F_IN + 255) / 256, 256, 0, stream>>>(x, cursor, xs, N_NODES * F_IN);

    transpose_f16_tiled<<<dim3((F_IN / 32) * (HID / 32), 1), 256, 0, stream>>>(W1, W1T, F_IN, HID);
    transpose_f16_tiled<<<dim3((HID / 32) * (HID / 32), N_LAYERS - 1), 256, 0, stream>>>(Wm, WmT, HID, HID);

    const int lgrid = N_NODES / 32;   // 625, exact
    // layer 1: K = F_IN, gather from xs, write fp16 hA (double-buffer ping-pong after)
    layer_fused<F_IN><<<lgrid, 256, 0, stream>>>(xs, W1T, ell_col, cursor, dinv, b1, dinv,
                                                 batch, hA, pool_sum);
    u16* cur = hA; u16* nxt = hB;
    for (int l = 0; l < N_LAYERS - 1; ++l) {
        const bool last = (l == N_LAYERS - 2);
        layer_fused<HID><<<lgrid, 256, 0, stream>>>(cur, WmT + (size_t)l * HID * HID,
                                                    ell_col, cursor, dinv,
                                                    bm + (size_t)l * HID,
                                                    last ? nullptr : dinv,
                                                    batch,
                                                    last ? nullptr : nxt, pool_sum);
        u16* t = cur; cur = nxt; nxt = t;
    }
    final_linear_kernel<<<2, 256, 0, stream>>>(pool_sum, batch, Wlin, blin, outp);
}